// Round 5
// baseline (1319.505 us; speedup 1.0000x reference)
//
#include <hip/hip_runtime.h>
#include <cstdint>
#include <cstddef>

// ---- problem constants ----
#define SEQ_L   4096
#define EMBED   1024
#define HEADS   16
#define WINSZ   128
#define SHIFTSZ 64
#define HD      64
#define NWIN    32
#define MTOT    32768          // B * L
#define ATT_SCALE 0.125f       // HD^-0.5

typedef __bf16 bf16x8 __attribute__((ext_vector_type(8)));
typedef float  f32x4  __attribute__((ext_vector_type(4)));
typedef float  f32x16 __attribute__((ext_vector_type(16)));

typedef __attribute__((address_space(3))) void       lds_void;
typedef const __attribute__((address_space(1))) void gbl_void;

// async global->LDS, 16B per lane; LDS dest is wave-uniform base + lane*16
#define GLDS16(g, s) __builtin_amdgcn_global_load_lds((gbl_void*)(g), (lds_void*)(s), 16, 0, 0)

__device__ __forceinline__ unsigned short f2bf(float f) {
    unsigned int u = __float_as_uint(f);
    u += 0x7fffu + ((u >> 16) & 1u);   // round-to-nearest-even
    return (unsigned short)(u >> 16);
}

// ---------------- weight f32 -> bf16 ----------------
__launch_bounds__(256)
__global__ void wconv(const float* __restrict__ in, unsigned short* __restrict__ out, int n)
{
    const int i = (blockIdx.x * 256 + threadIdx.x) * 4;
    if (i < n) {
        const float4 v = *(const float4*)(in + i);
        ushort4 o;
        o.x = f2bf(v.x); o.y = f2bf(v.y); o.z = f2bf(v.z); o.w = f2bf(v.w);
        *(ushort4*)(out + i) = o;
    }
}

// ---------------- LayerNorm, wave-per-row (optionally fused with roll) ----------------
__launch_bounds__(256)
__global__ void ln_kernel(const float* __restrict__ x, const float* __restrict__ gw,
                          const float* __restrict__ gb, unsigned short* __restrict__ out,
                          int shift)
{
    const int row  = blockIdx.x * 4 + (threadIdx.x >> 6);
    const int lane = threadIdx.x & 63;
    const int b    = row >> 12;
    const int lw   = row & 4095;
    const int src  = (b << 12) | ((lw + shift) & 4095);
    const float* xr = x + (size_t)src * EMBED;

    float4 v[4];
    float s = 0.f, q = 0.f;
#pragma unroll
    for (int j = 0; j < 4; ++j) {
        v[j] = ((const float4*)xr)[lane + j * 64];
        s += v[j].x + v[j].y + v[j].z + v[j].w;
        q += v[j].x * v[j].x + v[j].y * v[j].y + v[j].z * v[j].z + v[j].w * v[j].w;
    }
#pragma unroll
    for (int off = 32; off > 0; off >>= 1) {
        s += __shfl_xor(s, off);
        q += __shfl_xor(q, off);
    }
    const float mean = s * (1.0f / 1024.0f);
    const float rstd = rsqrtf(q * (1.0f / 1024.0f) - mean * mean + 1e-5f);

    unsigned short* orow = out + (size_t)row * EMBED;
#pragma unroll
    for (int j = 0; j < 4; ++j) {
        const float4 w4 = ((const float4*)gw)[lane + j * 64];
        const float4 b4 = ((const float4*)gb)[lane + j * 64];
        ushort4 o;
        o.x = f2bf((v[j].x - mean) * rstd * w4.x + b4.x);
        o.y = f2bf((v[j].y - mean) * rstd * w4.y + b4.y);
        o.z = f2bf((v[j].z - mean) * rstd * w4.z + b4.z);
        o.w = f2bf((v[j].w - mean) * rstd * w4.w + b4.w);
        ((ushort4*)orow)[lane + j * 64] = o;
    }
}

// ========== 256x256 8-phase GEMM, 32x32x16 MFMA core, one-phase-ahead prefetch ==========
// out[M,N] = A[M,K](bf16) * W[N,K]^T(bf16) + bias.
// EPI 0: bf16 out (QKV) | EPI 1: f32 out=x[rolled]+v at rolled row (proj)
// EPI 2: gelu->bf16 (MLP1) | EPI 3: f32 out += v (MLP2 residual)
//
// 8 waves (2M x 4N), per-wave C = 128x64 = 4x2 fragments of 32x32.
// LDS = 128 KiB double-buffered; swizzle byte ^= (row&7)<<4 (inverse on global
// source, forward on ds_read). Phase p computes m-frag p from A-bank (p&1)
// while loading m-frag p+1 into the other bank (counted lgkmcnt(4)); B-frags
// for tile t+1 prefetched after phase-3's MFMA. Stage slots: p0:(t+1).A0,
// p1:(t+1).A1, p2:(t+2).B0, p3:(t+2).B1; one counted vmcnt(2) per tile.
// A/B frag layout (32x32x16): row/col = lane&31, k = (lane>>5)*8 + i.
// C/D layout (verified m74/m101): col = lane&31, row = (reg&3)+8*(reg>>2)+4*(lane>>5).

__device__ __forceinline__ void stage_half(const unsigned short* __restrict__ g, int ldk,
                                           char* ldsbase, int tid)
{
    const int r  = tid >> 3;                    // 0..63
    const int cg = ((tid & 7) ^ (r & 7)) << 3;  // inverse-swizzled col (elems)
    GLDS16(g + (size_t)r        * ldk + cg, ldsbase + tid * 16);
    GLDS16(g + (size_t)(r + 64) * ldk + cg, ldsbase + 8192 + tid * 16);
}

__device__ __forceinline__ bf16x8 lds_frag(const char* half, int row, int koff)
{
    const int off = koff ^ ((row & 7) << 4);    // st-swizzle on read
    return *(const bf16x8*)(half + row * 128 + off);
}

template<int EPI, int K>
__launch_bounds__(512, 2)
__global__ void gemm256(const unsigned short* __restrict__ A, const unsigned short* __restrict__ W,
                        const float* __restrict__ bias, void* __restrict__ outv,
                        const float* __restrict__ resid, int M, int N)
{
    constexpr int NT = K >> 6;                  // K-tiles of 64 (even)

    __shared__ __align__(16) char lds[131072];
    const int tid = threadIdx.x;
    const int l   = tid & 63, w = tid >> 6;
    const int wm  = w >> 2, wn = w & 3;          // 2 x 4 waves
    const int lr5 = l & 31, hi5 = l >> 5;
    const int kbase = hi5 << 4;                  // byte offset of lane's k-slice
    const int br0   = (wn & 1) << 6;

    // XCD-aware bijective swizzle (all grids here are %8 == 0)
    int id = blockIdx.x;
    const int nwg = gridDim.x;
    id = (id & 7) * (nwg >> 3) + (id >> 3);
    const int Ntl = N >> 8;
    const int m0  = (id / Ntl) << 8;
    const int n0  = (id % Ntl) << 8;

#define HTB(b, ab, h) (lds + ((((b) << 1 | (ab)) << 1 | (h)) << 14))

    // prologue: t0 {A0,A1,B0,B1}, t1 {B0,B1}; drain t0 (vmcnt(4))
    stage_half(A + (size_t)m0         * K,      K, HTB(0,0,0), tid);
    stage_half(A + (size_t)(m0 + 128) * K,      K, HTB(0,0,1), tid);
    stage_half(W + (size_t)n0         * K,      K, HTB(0,1,0), tid);
    stage_half(W + (size_t)(n0 + 128) * K,      K, HTB(0,1,1), tid);
    stage_half(W + (size_t)n0         * K + 64, K, HTB(1,1,0), tid);
    stage_half(W + (size_t)(n0 + 128) * K + 64, K, HTB(1,1,1), tid);
    asm volatile("s_waitcnt vmcnt(4)" ::: "memory");
    __builtin_amdgcn_s_barrier();

    f32x16 acc[4][2];
#pragma unroll
    for (int f = 0; f < 4; ++f)
#pragma unroll
        for (int n = 0; n < 2; ++n)
            acc[f][n] = (f32x16)(0.f);

    bf16x8 bf[2][4], af0[4], af1[4];

#define LOAD_A_BANK(bank, AHP, MF)                                          \
    af##bank[0] = lds_frag(AHP, (MF) * 32 + lr5, 0  + kbase);               \
    af##bank[1] = lds_frag(AHP, (MF) * 32 + lr5, 32 + kbase);               \
    af##bank[2] = lds_frag(AHP, (MF) * 32 + lr5, 64 + kbase);               \
    af##bank[3] = lds_frag(AHP, (MF) * 32 + lr5, 96 + kbase);

#define LOAD_B(BHP)                                                         \
    _Pragma("unroll")                                                       \
    for (int nf = 0; nf < 2; ++nf)                                          \
        _Pragma("unroll")                                                   \
        for (int ks = 0; ks < 4; ++ks)                                      \
            bf[nf][ks] = lds_frag(BHP, br0 + nf * 32 + lr5, ks * 32 + kbase);

#define MFMA_BANK(bank, MF)                                                 \
    __builtin_amdgcn_s_setprio(1);                                          \
    _Pragma("unroll")                                                       \
    for (int ks = 0; ks < 4; ++ks) {                                        \
        acc[MF][0] = __builtin_amdgcn_mfma_f32_32x32x16_bf16(af##bank[ks], bf[0][ks], acc[MF][0], 0, 0, 0); \
        acc[MF][1] = __builtin_amdgcn_mfma_f32_32x32x16_bf16(af##bank[ks], bf[1][ks], acc[MF][1], 0, 0, 0); \
    }                                                                       \
    __builtin_amdgcn_s_setprio(0);

    // pre-issue t0.p0 operands: B(tile0) + A-bank0 m-frag0
    {
        const char* Bh0 = HTB(0, 1, wn >> 1);
        LOAD_B(Bh0)
        const char* Ah0 = HTB(0, 0, wm);
        LOAD_A_BANK(0, Ah0, 0)
    }

#define TILE(BUF)                                                              \
    {                                                                          \
        const char* Ah = HTB(BUF, 0, wm);                                      \
        const unsigned short* An = A + (size_t)m0 * K + (size_t)(t + 1) * 64;  \
        const unsigned short* Wn = W + (size_t)n0 * K + (size_t)(t + 2) * 64;  \
        /* ---- phase 0: compute mf0(bank0), load mf1->bank1 ---- */           \
        LOAD_A_BANK(1, Ah, 1)                                                  \
        if (t + 1 < NT) stage_half(An, K, HTB(BUF ^ 1, 0, 0), tid);            \
        asm volatile("s_waitcnt lgkmcnt(4)" ::: "memory");                     \
        MFMA_BANK(0, 0)                                                        \
        __builtin_amdgcn_s_barrier();                                          \
        /* ---- phase 1: compute mf1(bank1), load mf2->bank0 ---- */           \
        LOAD_A_BANK(0, Ah, 2)                                                  \
        if (t + 1 < NT) stage_half(An + (size_t)128 * K, K, HTB(BUF ^ 1, 0, 1), tid); \
        asm volatile("s_waitcnt lgkmcnt(4)" ::: "memory");                     \
        MFMA_BANK(1, 1)                                                        \
        __builtin_amdgcn_s_barrier();                                          \
        /* ---- phase 2: compute mf2(bank0), load mf3->bank1 ---- */           \
        LOAD_A_BANK(1, Ah, 3)                                                  \
        if (t + 2 < NT) stage_half(Wn, K, HTB(BUF, 1, 0), tid);                \
        asm volatile("s_waitcnt lgkmcnt(4)" ::: "memory");                     \
        MFMA_BANK(0, 2)                                                        \
        __builtin_amdgcn_s_barrier();                                          \
        /* ---- phase 3: compute mf3(bank1), prefetch next tile A+B ---- */    \
        if (t + 2 < NT) { asm volatile("s_waitcnt vmcnt(2)" ::: "memory"); }   \
        else            { asm volatile("s_waitcnt vmcnt(0)" ::: "memory"); }   \
        if (t + 1 < NT) { const char* AhN = HTB(BUF ^ 1, 0, wm); LOAD_A_BANK(0, AhN, 0) } \
        if (t + 2 < NT) stage_half(Wn + (size_t)128 * K, K, HTB(BUF, 1, 1), tid); \
        if (t + 1 < NT) { asm volatile("s_waitcnt lgkmcnt(4)" ::: "memory"); } \
        else            { asm volatile("s_waitcnt lgkmcnt(0)" ::: "memory"); } \
        MFMA_BANK(1, 3)                                                        \
        if (t + 1 < NT) {                                                      \
            const char* BhN = HTB(BUF ^ 1, 1, wn >> 1);                        \
            LOAD_B(BhN)                                                        \
        }                                                                      \
        __builtin_amdgcn_s_barrier();                                          \
    }

    int t;
    for (int u = 0; u < (NT >> 1); ++u) {
        t = 2 * u;     TILE(0)
        t = 2 * u + 1; TILE(1)
    }
#undef TILE
#undef LOAD_A_BANK
#undef LOAD_B
#undef MFMA_BANK
#undef HTB

    // ---- epilogue (32x32 C/D layout) ----
    const int cb = n0 + wn * 64;
    float bv[2];
#pragma unroll
    for (int nf = 0; nf < 2; ++nf) bv[nf] = bias[cb + nf * 32 + lr5];

#pragma unroll
    for (int mf = 0; mf < 4; ++mf) {
        const int mbase = m0 + wm * 128 + mf * 32 + hi5 * 4;
#pragma unroll
        for (int nf = 0; nf < 2; ++nf) {
            const int col = cb + nf * 32 + lr5;
#pragma unroll
            for (int reg = 0; reg < 16; ++reg) {
                const int m = mbase + (reg & 3) + ((reg >> 2) << 3);
                float v = acc[mf][nf][reg] + bv[nf];
                if constexpr (EPI == 0) {
                    ((unsigned short*)outv)[(size_t)m * N + col] = f2bf(v);
                } else if constexpr (EPI == 1) {
                    const int bb = m >> 12;
                    const int lw = m & 4095;
                    const int ll = (lw + SHIFTSZ) & 4095;
                    const size_t di = ((size_t)(bb << 12) + ll) * (size_t)N + col;
                    ((float*)outv)[di] = resid[di] + v;
                } else if constexpr (EPI == 2) {
                    const float g = 0.5f * v * (1.0f + erff(v * 0.70710678118654752f));
                    ((unsigned short*)outv)[(size_t)m * N + col] = f2bf(g);
                } else {
                    float* o = (float*)outv;
                    const size_t di = (size_t)m * N + col;
                    o[di] = o[di] + v;
                }
            }
        }
    }
}

// ---------------- windowed attention: one block per (window, head) ----------------
__device__ __forceinline__ bf16x8 vt_frag(const char* vt, int d, int kbyte)
{
    const int key = ((d >> 3) & 7) << 4;
    return *(const bf16x8*)(vt + d * 272 + (kbyte ^ key));
}

__launch_bounds__(256, 2)
__global__ void attn_kernel(const unsigned short* __restrict__ qkv, const float* __restrict__ rpb,
                            unsigned short* __restrict__ outp)
{
    __shared__ __align__(16) char          Ks[128 * 128];       // 16 KB, swizzled [128][64] bf16
    __shared__ __align__(16) unsigned short P[WINSZ][136];      // 34 KB
    __shared__ __align__(16) unsigned short VTl[64 * 136];      // 17 KB, swizzled V^T

    const int t   = threadIdx.x;
    const int l   = t & 63;
    const int w   = t >> 6;
    const int lr  = l & 15;
    const int lq  = l >> 4;
    const int lk  = lq * 8;
    const int blk = blockIdx.x;
    const int win = blk >> 4;
    const int h   = blk & 15;
    const bool masked = ((win & (NWIN - 1)) == NWIN - 1);

    const unsigned short* qb = qkv + (size_t)(win * WINSZ) * (3 * EMBED) + h * HD;
    const unsigned short* kb = qb + EMBED;
    const unsigned short* vb = qb + 2 * EMBED;

    // ---- stage K: inverse-swizzled source, linear LDS dest ----
    {
        const int c = t & 7;
#pragma unroll
        for (int p = 0; p < 4; ++p) {
            const int r  = (t >> 3) + p * 32;
            const int cg = (c ^ (r & 7)) << 3;
            GLDS16(kb + (size_t)r * (3 * EMBED) + cg, Ks + p * 4096 + t * 16);
        }
    }
    // ---- stage V^T: coalesced reads, swizzled transpose writes ----
    {
        const int c = t & 7;
#pragma unroll
        for (int p = 0; p < 4; ++p) {
            const int k = (t >> 3) + p * 32;
            const uint4 v = *(const uint4*)(vb + (size_t)k * (3 * EMBED) + c * 8);
            const unsigned int vals[4] = {v.x, v.y, v.z, v.w};
            char* base = (char*)VTl;
#pragma unroll
            for (int e2 = 0; e2 < 4; ++e2) {
                const int d0 = c * 8 + e2 * 2;
                const int key = c << 4;
                *(unsigned short*)(base + d0 * 272 + ((2 * k) ^ key))       = (unsigned short)(vals[e2] & 0xffff);
                *(unsigned short*)(base + (d0 + 1) * 272 + ((2 * k) ^ key)) = (unsigned short)(vals[e2] >> 16);
            }
        }
    }
    asm volatile("s_waitcnt vmcnt(0)" ::: "memory");
    __syncthreads();

    // ---- QK^T ----
    const int mrow = w * 32;
    f32x4 sacc[2][8];
#pragma unroll
    for (int a = 0; a < 2; ++a)
#pragma unroll
        for (int b = 0; b < 8; ++b)
            sacc[a][b] = (f32x4){0.f, 0.f, 0.f, 0.f};

#pragma unroll
    for (int ks = 0; ks < 2; ++ks) {
        const int kby = ks * 64 + lq * 16;
        bf16x8 aq[2], bk8[8];
#pragma unroll
        for (int mi = 0; mi < 2; ++mi)
            aq[mi] = *(const bf16x8*)(qb + (size_t)(mrow + mi * 16 + lr) * (3 * EMBED) + ks * 32 + lk);
#pragma unroll
        for (int ni = 0; ni < 8; ++ni)
            bk8[ni] = lds_frag(Ks, ni * 16 + lr, kby);
#pragma unroll
        for (int mi = 0; mi < 2; ++mi)
#pragma unroll
            for (int ni = 0; ni < 8; ++ni)
                sacc[mi][ni] = __builtin_amdgcn_mfma_f32_16x16x32_bf16(aq[mi], bk8[ni], sacc[mi][ni], 0, 0, 0);
    }

    // ---- in-register softmax per row ----
#pragma unroll
    for (int mi = 0; mi < 2; ++mi)
#pragma unroll
        for (int r = 0; r < 4; ++r) {
            const int i = mrow + mi * 16 + lq * 4 + r;
            float v[8];
            float mx = -1e30f;
#pragma unroll
            for (int ni = 0; ni < 8; ++ni) {
                const int j = ni * 16 + lr;
                float sv = sacc[mi][ni][r] * ATT_SCALE + rpb[(j - i + WINSZ - 1) * HEADS + h];
                if (masked && ((i >= SHIFTSZ) != (j >= SHIFTSZ))) sv -= 100.0f;
                v[ni] = sv;
                mx = fmaxf(mx, sv);
            }
#pragma unroll
            for (int s = 1; s < 16; s <<= 1) mx = fmaxf(mx, __shfl_xor(mx, s));
            float sm = 0.f;
#pragma unroll
            for (int ni = 0; ni < 8; ++ni) {
                const float p = __expf(v[ni] - mx);
                v[ni] = p;
                sm += p;
            }
#pragma unroll
            for (int s = 1; s < 16; s <<= 1) sm += __shfl_xor(sm, s);
            const float rs = 1.0f / sm;
#pragma unroll
            for (int ni = 0; ni < 8; ++ni)
                P[i][ni * 16 + lr] = f2bf(v[ni] * rs);
        }

    __syncthreads();

    // ---- PV ----
    f32x4 oacc[2][4];
#pragma unroll
    for (int a = 0; a < 2; ++a)
#pragma unroll
        for (int b = 0; b < 4; ++b)
            oacc[a][b] = (f32x4){0.f, 0.f, 0.f, 0.f};

#pragma unroll
    for (int ks = 0; ks < 4; ++ks) {
        const int k0 = ks * 32;
        bf16x8 ap[2], av[4];
#pragma unroll
        for (int mi = 0; mi < 2; ++mi)
            ap[mi] = *(const bf16x8*)(&P[mrow + mi * 16 + lr][k0 + lk]);
#pragma unroll
        for (int ni = 0; ni < 4; ++ni)
            av[ni] = vt_frag((const char*)VTl, ni * 16 + lr, k0 * 2 + lq * 16);
#pragma unroll
        for (int mi = 0; mi < 2; ++mi)
#pragma unroll
            for (int ni = 0; ni < 4; ++ni)
                oacc[mi][ni] = __builtin_amdgcn_mfma_f32_16x16x32_bf16(ap[mi], av[ni], oacc[mi][ni], 0, 0, 0);
    }

    unsigned short* ob = outp + (size_t)(win * WINSZ) * EMBED + h * HD;
#pragma unroll
    for (int mi = 0; mi < 2; ++mi)
#pragma unroll
        for (int ni = 0; ni < 4; ++ni)
#pragma unroll
            for (int r = 0; r < 4; ++r) {
                const int i = mrow + mi * 16 + lq * 4 + r;
                const int d = ni * 16 + lr;
                ob[(size_t)i * EMBED + d] = f2bf(oacc[mi][ni][r]);
            }
}

// ---------------- launcher ----------------
extern "C" void kernel_launch(void* const* d_in, const int* in_sizes, int n_in,
                              void* d_out, int out_size, void* d_ws, size_t ws_size,
                              hipStream_t stream)
{
    const float* x      = (const float*)d_in[0];
    const float* qkv_w  = (const float*)d_in[1];
    const float* qkv_b  = (const float*)d_in[2];
    const float* proj_w = (const float*)d_in[3];
    const float* proj_b = (const float*)d_in[4];
    const float* rpb    = (const float*)d_in[5];
    const float* n1w    = (const float*)d_in[6];
    const float* n1b    = (const float*)d_in[7];
    const float* n2w    = (const float*)d_in[8];
    const float* n2b    = (const float*)d_in[9];
    const float* w1     = (const float*)d_in[10];
    const float* b1     = (const float*)d_in[11];
    const float* w2     = (const float*)d_in[12];
    const float* b2     = (const float*)d_in[13];
    float* out = (float*)d_out;

    unsigned short* wqkv  = (unsigned short*)d_ws;                    // 3072*1024
    unsigned short* wproj = wqkv  + (size_t)3072 * 1024;              // 1024*1024
    unsigned short* wm1   = wproj + (size_t)1024 * 1024;              // 4096*1024
    unsigned short* wm2   = wm1   + (size_t)4096 * 1024;              // 4096*1024
    unsigned short* bufA  = wm2   + (size_t)4096 * 1024;              // 32768*1024
    unsigned short* bufB  = bufA  + (size_t)MTOT * EMBED;             // 32768*3072

    wconv<<<3072, 256, 0, stream>>>(qkv_w, wqkv, 3 * EMBED * EMBED);
    wconv<<<1024, 256, 0, stream>>>(proj_w, wproj, EMBED * EMBED);
    wconv<<<4096, 256, 0, stream>>>(w1, wm1, 4 * EMBED * EMBED);
    wconv<<<4096, 256, 0, stream>>>(w2, wm2, 4 * EMBED * EMBED);

    // h = LN1(x) rolled by -SHIFT
    ln_kernel<<<8192, 256, 0, stream>>>(x, n1w, n1b, bufA, SHIFTSZ);

    // qkv = h @ qkv_w^T + qkv_b   (M=32768, N=3072, K=1024)
    gemm256<0, 1024><<<dim3(1536), 512, 0, stream>>>(bufA, wqkv, qkv_b, bufB, nullptr, MTOT, 3 * EMBED);

    // windowed attention -> bufA
    attn_kernel<<<4096, 256, 0, stream>>>(bufB, rpb, bufA);

    // x2 = x + roll(attn @ proj_w^T + proj_b, +SHIFT)
    gemm256<1, 1024><<<dim3(512), 512, 0, stream>>>(bufA, wproj, proj_b, out, x, MTOT, EMBED);

    // h2 = LN2(x2)
    ln_kernel<<<8192, 256, 0, stream>>>(out, n2w, n2b, bufA, 0);

    // MLP chunked (2 x 16384 rows)
    for (int c = 0; c < 2; ++c) {
        const size_t r0 = (size_t)c * 16384;
        gemm256<2, 1024><<<dim3(1024), 512, 0, stream>>>(bufA + r0 * EMBED, wm1, b1, bufB, nullptr,
                                                         16384, 4 * EMBED);
        gemm256<3, 4096><<<dim3(256), 512, 0, stream>>>(bufB, wm2, b2, out + r0 * EMBED, nullptr,
                                                        16384, EMBED);
    }
}

// Round 7
// 1151.401 us; speedup vs baseline: 1.1460x; 1.1460x over previous
//
#include <hip/hip_runtime.h>
#include <cstdint>
#include <cstddef>

// ---- problem constants ----
#define SEQ_L   4096
#define EMBED   1024
#define HEADS   16
#define WINSZ   128
#define SHIFTSZ 64
#define HD      64
#define NWIN    32
#define MTOT    32768          // B * L
#define ATT_SCALE 0.125f       // HD^-0.5

typedef __bf16 bf16x8 __attribute__((ext_vector_type(8)));
typedef float  f32x4  __attribute__((ext_vector_type(4)));

typedef __attribute__((address_space(3))) void       lds_void;
typedef const __attribute__((address_space(1))) void gbl_void;

// async global->LDS, 16B per lane; LDS dest is wave-uniform base + lane*16
#define GLDS16(g, s) __builtin_amdgcn_global_load_lds((gbl_void*)(g), (lds_void*)(s), 16, 0, 0)

__device__ __forceinline__ unsigned short f2bf(float f) {
    unsigned int u = __float_as_uint(f);
    u += 0x7fffu + ((u >> 16) & 1u);   // round-to-nearest-even
    return (unsigned short)(u >> 16);
}

// ---------------- weight f32 -> bf16 (4 tensors in one launch) ----------------
__launch_bounds__(256)
__global__ void wconv4(const float* __restrict__ s0, const float* __restrict__ s1,
                       const float* __restrict__ s2, const float* __restrict__ s3,
                       unsigned short* __restrict__ d0, unsigned short* __restrict__ d1,
                       unsigned short* __restrict__ d2, unsigned short* __restrict__ d3)
{
    const int b = blockIdx.x;
    const float* s; unsigned short* d; int off;
    if (b < 3072)      { s = s0; d = d0; off = b; }
    else if (b < 4096) { s = s1; d = d1; off = b - 3072; }
    else if (b < 8192) { s = s2; d = d2; off = b - 4096; }
    else               { s = s3; d = d3; off = b - 8192; }
    const int i = (off * 256 + threadIdx.x) * 4;
    const float4 v = *(const float4*)(s + i);
    ushort4 o;
    o.x = f2bf(v.x); o.y = f2bf(v.y); o.z = f2bf(v.z); o.w = f2bf(v.w);
    *(ushort4*)(d + i) = o;
}

// ---------------- LayerNorm, wave-per-row (optionally fused with roll) ----------------
__launch_bounds__(256)
__global__ void ln_kernel(const float* __restrict__ x, const float* __restrict__ gw,
                          const float* __restrict__ gb, unsigned short* __restrict__ out,
                          int shift)
{
    const int row  = blockIdx.x * 4 + (threadIdx.x >> 6);
    const int lane = threadIdx.x & 63;
    const int b    = row >> 12;
    const int lw   = row & 4095;
    const int src  = (b << 12) | ((lw + shift) & 4095);
    const float* xr = x + (size_t)src * EMBED;

    float4 v[4];
    float s = 0.f, q = 0.f;
#pragma unroll
    for (int j = 0; j < 4; ++j) {
        v[j] = ((const float4*)xr)[lane + j * 64];
        s += v[j].x + v[j].y + v[j].z + v[j].w;
        q += v[j].x * v[j].x + v[j].y * v[j].y + v[j].z * v[j].z + v[j].w * v[j].w;
    }
#pragma unroll
    for (int off = 32; off > 0; off >>= 1) {
        s += __shfl_xor(s, off);
        q += __shfl_xor(q, off);
    }
    const float mean = s * (1.0f / 1024.0f);
    const float rstd = rsqrtf(q * (1.0f / 1024.0f) - mean * mean + 1e-5f);

    unsigned short* orow = out + (size_t)row * EMBED;
#pragma unroll
    for (int j = 0; j < 4; ++j) {
        const float4 w4 = ((const float4*)gw)[lane + j * 64];
        const float4 b4 = ((const float4*)gb)[lane + j * 64];
        ushort4 o;
        o.x = f2bf((v[j].x - mean) * rstd * w4.x + b4.x);
        o.y = f2bf((v[j].y - mean) * rstd * w4.y + b4.y);
        o.z = f2bf((v[j].z - mean) * rstd * w4.z + b4.z);
        o.w = f2bf((v[j].w - mean) * rstd * w4.w + b4.w);
        ((ushort4*)orow)[lane + j * 64] = o;
    }
}

// ================= 256x256 8-phase GEMM, one-phase-ahead reg prefetch =================
// (verbatim Round-3 kernel: known-good, 221 us QKV, MfmaUtil 41.9%, 0 conflicts)
// out[M,N] = A[M,K](bf16) * W[N,K]^T(bf16) + bias.
// EPI 0: bf16 out (QKV) | EPI 1: f32 out=x[rolled]+v at rolled row (proj)
// EPI 2: gelu->bf16 (MLP1) | EPI 3: f32 out += v (MLP2 residual)

__device__ __forceinline__ void stage_half(const unsigned short* __restrict__ g, int ldk,
                                           char* ldsbase, int tid)
{
    const int r  = tid >> 3;                    // 0..63
    const int cg = ((tid & 7) ^ (r & 7)) << 3;  // inverse-swizzled col (elems)
    GLDS16(g + (size_t)r        * ldk + cg, ldsbase + tid * 16);
    GLDS16(g + (size_t)(r + 64) * ldk + cg, ldsbase + 8192 + tid * 16);
}

__device__ __forceinline__ bf16x8 lds_frag(const char* half, int row, int koff)
{
    const int off = koff ^ ((row & 7) << 4);    // st-swizzle on read
    return *(const bf16x8*)(half + row * 128 + off);
}

template<int EPI>
__launch_bounds__(512, 2)
__global__ void gemm256(const unsigned short* __restrict__ A, const unsigned short* __restrict__ W,
                        const float* __restrict__ bias, void* __restrict__ outv,
                        const float* __restrict__ resid, int M, int N, int K)
{
    __shared__ __align__(16) char lds[131072];
    const int tid = threadIdx.x;
    const int l   = tid & 63, w = tid >> 6;
    const int wm  = w >> 2, wn = w & 3;          // 2 x 4 waves
    const int lr  = l & 15, hi = l >> 4;
    const int k0off = hi << 4;                   // byte offset of k-slice within row
    const int br0   = (wn & 1) << 6;

    // XCD-aware bijective swizzle (all grids here are %8 == 0)
    int id = blockIdx.x;
    const int nwg = gridDim.x;
    id = (id & 7) * (nwg >> 3) + (id >> 3);
    const int Ntl = N >> 8;
    const int m0  = (id / Ntl) << 8;
    const int n0  = (id % Ntl) << 8;
    const int NT  = K >> 6;                      // K-tiles of 64

#define HTB(b, ab, h) (lds + ((((b) << 1 | (ab)) << 1 | (h)) << 14))

    // prologue: t0 {A0,A1,B0,B1}, t1 {B0,B1}; drain t0 (vmcnt(4))
    stage_half(A + (size_t)m0         * K,      K, HTB(0,0,0), tid);
    stage_half(A + (size_t)(m0 + 128) * K,      K, HTB(0,0,1), tid);
    stage_half(W + (size_t)n0         * K,      K, HTB(0,1,0), tid);
    stage_half(W + (size_t)(n0 + 128) * K,      K, HTB(0,1,1), tid);
    stage_half(W + (size_t)n0         * K + 64, K, HTB(1,1,0), tid);
    stage_half(W + (size_t)(n0 + 128) * K + 64, K, HTB(1,1,1), tid);
    asm volatile("s_waitcnt vmcnt(4)" ::: "memory");
    __builtin_amdgcn_s_barrier();

    f32x4 acc[8][4];
#pragma unroll
    for (int f = 0; f < 8; ++f)
#pragma unroll
        for (int n = 0; n < 4; ++n)
            acc[f][n] = (f32x4){0.f, 0.f, 0.f, 0.f};

    bf16x8 bf[4][2], af0[2][2], af1[2][2];

#define LOAD_A_BANK(bank, AHP, F0)                                          \
    af##bank[0][0] = lds_frag(AHP, (F0) * 16 + lr,      k0off);             \
    af##bank[0][1] = lds_frag(AHP, (F0) * 16 + lr,      64 + k0off);        \
    af##bank[1][0] = lds_frag(AHP, (F0) * 16 + 16 + lr, k0off);             \
    af##bank[1][1] = lds_frag(AHP, (F0) * 16 + 16 + lr, 64 + k0off);

#define MFMA_BANK(bank, F0)                                                 \
    __builtin_amdgcn_s_setprio(1);                                          \
    _Pragma("unroll")                                                       \
    for (int n = 0; n < 4; ++n) {                                           \
        acc[F0][n]       = __builtin_amdgcn_mfma_f32_16x16x32_bf16(af##bank[0][0], bf[n][0], acc[F0][n], 0, 0, 0);       \
        acc[F0][n]       = __builtin_amdgcn_mfma_f32_16x16x32_bf16(af##bank[0][1], bf[n][1], acc[F0][n], 0, 0, 0);       \
        acc[(F0) + 1][n] = __builtin_amdgcn_mfma_f32_16x16x32_bf16(af##bank[1][0], bf[n][0], acc[(F0) + 1][n], 0, 0, 0); \
        acc[(F0) + 1][n] = __builtin_amdgcn_mfma_f32_16x16x32_bf16(af##bank[1][1], bf[n][1], acc[(F0) + 1][n], 0, 0, 0); \
    }                                                                       \
    __builtin_amdgcn_s_setprio(0);

    // pre-issue t0.p0 operands: B(0) + A-bank0 f0,f1
    {
        const char* Bh0 = HTB(0, 1, wn >> 1);
#pragma unroll
        for (int n = 0; n < 4; ++n) {
            bf[n][0] = lds_frag(Bh0, br0 + n * 16 + lr, k0off);
            bf[n][1] = lds_frag(Bh0, br0 + n * 16 + lr, 64 + k0off);
        }
        const char* Ah0 = HTB(0, 0, wm);
        LOAD_A_BANK(0, Ah0, 0)
    }

#define TILE(BUF)                                                              \
    {                                                                          \
        const char* Ah = HTB(BUF, 0, wm);                                      \
        const unsigned short* An = A + (size_t)m0 * K + (size_t)(t + 1) * 64;  \
        const unsigned short* Wn = W + (size_t)n0 * K + (size_t)(t + 2) * 64;  \
        /* ---- phase 0 ---- */                                                \
        LOAD_A_BANK(1, Ah, 2)                                                  \
        if (t + 1 < NT) stage_half(An, K, HTB(BUF ^ 1, 0, 0), tid);            \
        asm volatile("s_waitcnt lgkmcnt(4)" ::: "memory");                     \
        MFMA_BANK(0, 0)                                                        \
        __builtin_amdgcn_s_barrier();                                          \
        /* ---- phase 1 ---- */                                                \
        LOAD_A_BANK(0, Ah, 4)                                                  \
        if (t + 1 < NT) stage_half(An + (size_t)128 * K, K, HTB(BUF ^ 1, 0, 1), tid); \
        asm volatile("s_waitcnt lgkmcnt(4)" ::: "memory");                     \
        MFMA_BANK(1, 2)                                                        \
        __builtin_amdgcn_s_barrier();                                          \
        /* ---- phase 2 ---- */                                                \
        LOAD_A_BANK(1, Ah, 6)                                                  \
        if (t + 2 < NT) stage_half(Wn, K, HTB(BUF, 1, 0), tid);                \
        asm volatile("s_waitcnt lgkmcnt(4)" ::: "memory");                     \
        MFMA_BANK(0, 4)                                                        \
        __builtin_amdgcn_s_barrier();                                          \
        /* ---- phase 3 ---- */                                                \
        if (t + 2 < NT) { asm volatile("s_waitcnt vmcnt(2)" ::: "memory"); }   \
        else            { asm volatile("s_waitcnt vmcnt(0)" ::: "memory"); }   \
        if (t + 1 < NT) { const char* AhN = HTB(BUF ^ 1, 0, wm); LOAD_A_BANK(0, AhN, 0) } \
        if (t + 2 < NT) stage_half(Wn + (size_t)128 * K, K, HTB(BUF, 1, 1), tid); \
        if (t + 1 < NT) { asm volatile("s_waitcnt lgkmcnt(4)" ::: "memory"); } \
        else            { asm volatile("s_waitcnt lgkmcnt(0)" ::: "memory"); } \
        MFMA_BANK(1, 6)                                                        \
        if (t + 1 < NT) {                                                      \
            const char* BhN = HTB(BUF ^ 1, 1, wn >> 1);                        \
            _Pragma("unroll")                                                  \
            for (int n = 0; n < 4; ++n) {                                      \
                bf[n][0] = lds_frag(BhN, br0 + n * 16 + lr, k0off);            \
                bf[n][1] = lds_frag(BhN, br0 + n * 16 + lr, 64 + k0off);       \
            }                                                                  \
        }                                                                      \
        __builtin_amdgcn_s_barrier();                                          \
    }

    int t;
    for (int u = 0; u < (NT >> 1); ++u) {
        t = 2 * u;     TILE(0)
        t = 2 * u + 1; TILE(1)
    }
#undef TILE
#undef LOAD_A_BANK
#undef MFMA_BANK
#undef HTB

    // ---- epilogue ----
    const int cb = n0 + wn * 64;
    float bv[4];
#pragma unroll
    for (int n = 0; n < 4; ++n) bv[n] = bias[cb + n * 16 + lr];

#pragma unroll
    for (int f = 0; f < 8; ++f) {
        const int mbase = m0 + wm * 128 + f * 16 + hi * 4;
#pragma unroll
        for (int n = 0; n < 4; ++n) {
            const int col = cb + n * 16 + lr;
#pragma unroll
            for (int r = 0; r < 4; ++r) {
                const int m = mbase + r;
                float v = acc[f][n][r] + bv[n];
                if constexpr (EPI == 0) {
                    ((unsigned short*)outv)[(size_t)m * N + col] = f2bf(v);
                } else if constexpr (EPI == 1) {
                    const int bb = m >> 12;
                    const int lw = m & 4095;
                    const int ll = (lw + SHIFTSZ) & 4095;
                    const size_t di = ((size_t)(bb << 12) + ll) * (size_t)N + col;
                    ((float*)outv)[di] = resid[di] + v;
                } else if constexpr (EPI == 2) {
                    const float g = 0.5f * v * (1.0f + erff(v * 0.70710678118654752f));
                    ((unsigned short*)outv)[(size_t)m * N + col] = f2bf(g);
                } else {
                    float* o = (float*)outv;
                    const size_t di = (size_t)m * N + col;
                    o[di] = o[di] + v;
                }
            }
        }
    }
}

// ---------------- windowed attention: one block per (window, head) ----------------
// K staged via global_load_lds into XOR-swizzled LDS; V via coalesced uint4 +
// swizzled transpose writes. Q fragments hoisted to kernel entry (latency
// overlaps staging). rpb column staged to LDS (replaces 64 scattered VMEM
// gathers per lane in the softmax).
__device__ __forceinline__ bf16x8 vt_frag(const char* vt, int d, int kbyte)
{
    const int key = ((d >> 3) & 7) << 4;
    return *(const bf16x8*)(vt + d * 272 + (kbyte ^ key));
}

__launch_bounds__(256, 2)
__global__ void attn_kernel(const unsigned short* __restrict__ qkv, const float* __restrict__ rpb,
                            unsigned short* __restrict__ outp)
{
    __shared__ __align__(16) char          Ks[128 * 128];       // 16 KB, swizzled [128][64] bf16
    __shared__ __align__(16) unsigned short P[WINSZ][136];      // 34 KB
    __shared__ __align__(16) unsigned short VTl[64 * 136];      // 17 KB, swizzled V^T
    __shared__ __align__(16) float          rpbl[256];          // 1 KB, rpb[:, h]

    const int t   = threadIdx.x;
    const int l   = t & 63;
    const int w   = t >> 6;
    const int lr  = l & 15;
    const int lq  = l >> 4;
    const int lk  = lq * 8;
    const int blk = blockIdx.x;
    const int win = blk >> 4;
    const int h   = blk & 15;
    const bool masked = ((win & (NWIN - 1)) == NWIN - 1);

    const unsigned short* qb = qkv + (size_t)(win * WINSZ) * (3 * EMBED) + h * HD;
    const unsigned short* kb = qb + EMBED;
    const unsigned short* vb = qb + 2 * EMBED;
    const int mrow = w * 32;

    // ---- hoist Q fragment loads (latency hides under K/V staging) ----
    bf16x8 aqr[2][2];
#pragma unroll
    for (int ks = 0; ks < 2; ++ks)
#pragma unroll
        for (int mi = 0; mi < 2; ++mi)
            aqr[ks][mi] = *(const bf16x8*)(qb + (size_t)(mrow + mi * 16 + lr) * (3 * EMBED) + ks * 32 + lk);

    // ---- stage rpb column h ----
    if (t < 255) rpbl[t] = rpb[t * HEADS + h];

    // ---- stage K: inverse-swizzled source, linear LDS dest ----
    {
        const int c = t & 7;
#pragma unroll
        for (int p = 0; p < 4; ++p) {
            const int r  = (t >> 3) + p * 32;
            const int cg = (c ^ (r & 7)) << 3;
            GLDS16(kb + (size_t)r * (3 * EMBED) + cg, Ks + p * 4096 + t * 16);
        }
    }
    // ---- stage V^T: coalesced reads, swizzled transpose writes ----
    {
        const int c = t & 7;
#pragma unroll
        for (int p = 0; p < 4; ++p) {
            const int k = (t >> 3) + p * 32;
            const uint4 v = *(const uint4*)(vb + (size_t)k * (3 * EMBED) + c * 8);
            const unsigned int vals[4] = {v.x, v.y, v.z, v.w};
            char* base = (char*)VTl;
#pragma unroll
            for (int e2 = 0; e2 < 4; ++e2) {
                const int d0 = c * 8 + e2 * 2;
                const int key = c << 4;
                *(unsigned short*)(base + d0 * 272 + ((2 * k) ^ key))       = (unsigned short)(vals[e2] & 0xffff);
                *(unsigned short*)(base + (d0 + 1) * 272 + ((2 * k) ^ key)) = (unsigned short)(vals[e2] >> 16);
            }
        }
    }
    asm volatile("s_waitcnt vmcnt(0)" ::: "memory");
    __syncthreads();

    // ---- QK^T ----
    f32x4 sacc[2][8];
#pragma unroll
    for (int a = 0; a < 2; ++a)
#pragma unroll
        for (int b = 0; b < 8; ++b)
            sacc[a][b] = (f32x4){0.f, 0.f, 0.f, 0.f};

#pragma unroll
    for (int ks = 0; ks < 2; ++ks) {
        const int kby = ks * 64 + lq * 16;
        bf16x8 bk8[8];
#pragma unroll
        for (int ni = 0; ni < 8; ++ni)
            bk8[ni] = lds_frag(Ks, ni * 16 + lr, kby);
#pragma unroll
        for (int mi = 0; mi < 2; ++mi)
#pragma unroll
            for (int ni = 0; ni < 8; ++ni)
                sacc[mi][ni] = __builtin_amdgcn_mfma_f32_16x16x32_bf16(aqr[ks][mi], bk8[ni], sacc[mi][ni], 0, 0, 0);
    }

    // ---- in-register softmax per row ----
#pragma unroll
    for (int mi = 0; mi < 2; ++mi)
#pragma unroll
        for (int r = 0; r < 4; ++r) {
            const int i = mrow + mi * 16 + lq * 4 + r;
            float v[8];
            float mx = -1e30f;
#pragma unroll
            for (int ni = 0; ni < 8; ++ni) {
                const int j = ni * 16 + lr;
                float sv = sacc[mi][ni][r] * ATT_SCALE + rpbl[j - i + WINSZ - 1];
                if (masked && ((i >= SHIFTSZ) != (j >= SHIFTSZ))) sv -= 100.0f;
                v[ni] = sv;
                mx = fmaxf(mx, sv);
            }
#pragma unroll
            for (int s = 1; s < 16; s <<= 1) mx = fmaxf(mx, __shfl_xor(mx, s));
            float sm = 0.f;
#pragma unroll
            for (int ni = 0; ni < 8; ++ni) {
                const float p = __expf(v[ni] - mx);
                v[ni] = p;
                sm += p;
            }
#pragma unroll
            for (int s = 1; s < 16; s <<= 1) sm += __shfl_xor(sm, s);
            const float rs = 1.0f / sm;
#pragma unroll
            for (int ni = 0; ni < 8; ++ni)
                P[i][ni * 16 + lr] = f2bf(v[ni] * rs);
        }

    __syncthreads();

    // ---- PV ----
    f32x4 oacc[2][4];
#pragma unroll
    for (int a = 0; a < 2; ++a)
#pragma unroll
        for (int b = 0; b < 4; ++b)
            oacc[a][b] = (f32x4){0.f, 0.f, 0.f, 0.f};

#pragma unroll
    for (int ks = 0; ks < 4; ++ks) {
        const int k0 = ks * 32;
        bf16x8 ap[2], av[4];
#pragma unroll
        for (int mi = 0; mi < 2; ++mi)
            ap[mi] = *(const bf16x8*)(&P[mrow + mi * 16 + lr][k0 + lk]);
#pragma unroll
        for (int ni = 0; ni < 4; ++ni)
            av[ni] = vt_frag((const char*)VTl, ni * 16 + lr, k0 * 2 + lq * 16);
#pragma unroll
        for (int mi = 0; mi < 2; ++mi)
#pragma unroll
            for (int ni = 0; ni < 4; ++ni)
                oacc[mi][ni] = __builtin_amdgcn_mfma_f32_16x16x32_bf16(ap[mi], av[ni], oacc[mi][ni], 0, 0, 0);
    }

    unsigned short* ob = outp + (size_t)(win * WINSZ) * EMBED + h * HD;
#pragma unroll
    for (int mi = 0; mi < 2; ++mi)
#pragma unroll
        for (int ni = 0; ni < 4; ++ni)
#pragma unroll
            for (int r = 0; r < 4; ++r) {
                const int i = mrow + mi * 16 + lq * 4 + r;
                const int d = ni * 16 + lr;
                ob[(size_t)i * EMBED + d] = f2bf(oacc[mi][ni][r]);
            }
}

// ---------------- launcher ----------------
extern "C" void kernel_launch(void* const* d_in, const int* in_sizes, int n_in,
                              void* d_out, int out_size, void* d_ws, size_t ws_size,
                              hipStream_t stream)
{
    const float* x      = (const float*)d_in[0];
    const float* qkv_w  = (const float*)d_in[1];
    const float* qkv_b  = (const float*)d_in[2];
    const float* proj_w = (const float*)d_in[3];
    const float* proj_b = (const float*)d_in[4];
    const float* rpb    = (const float*)d_in[5];
    const float* n1w    = (const float*)d_in[6];
    const float* n1b    = (const float*)d_in[7];
    const float* n2w    = (const float*)d_in[8];
    const float* n2b    = (const float*)d_in[9];
    const float* w1     = (const float*)d_in[10];
    const float* b1     = (const float*)d_in[11];
    const float* w2     = (const float*)d_in[12];
    const float* b2     = (const float*)d_in[13];
    float* out = (float*)d_out;

    unsigned short* wqkv  = (unsigned short*)d_ws;                    // 3072*1024
    unsigned short* wproj = wqkv  + (size_t)3072 * 1024;              // 1024*1024
    unsigned short* wm1   = wproj + (size_t)1024 * 1024;              // 4096*1024
    unsigned short* wm2   = wm1   + (size_t)4096 * 1024;              // 4096*1024
    unsigned short* bufA  = wm2   + (size_t)4096 * 1024;              // 32768*1024
    unsigned short* bufB  = bufA  + (size_t)MTOT * EMBED;             // 32768*3072

    // all 4 weight conversions in one launch
    wconv4<<<12288, 256, 0, stream>>>(qkv_w, proj_w, w1, w2, wqkv, wproj, wm1, wm2);

    // h = LN1(x) rolled by -SHIFT
    ln_kernel<<<8192, 256, 0, stream>>>(x, n1w, n1b, bufA, SHIFTSZ);

    // qkv = h @ qkv_w^T + qkv_b   (M=32768, N=3072, K=1024)
    gemm256<0><<<dim3(1536), 512, 0, stream>>>(bufA, wqkv, qkv_b, bufB, nullptr, MTOT, 3 * EMBED, EMBED);

    // windowed attention -> bufA
    attn_kernel<<<4096, 256, 0, stream>>>(bufB, rpb, bufA);

    // x2 = x + roll(attn @ proj_w^T + proj_b, +SHIFT)
    gemm256<1><<<dim3(512), 512, 0, stream>>>(bufA, wproj, proj_b, out, x, MTOT, EMBED, EMBED);

    // h2 = LN2(x2)
    ln_kernel<<<8192, 256, 0, stream>>>(out, n2w, n2b, bufA, 0);

    // MLP chunked (2 x 16384 rows)
    for (int c = 0; c < 2; ++c) {
        const size_t r0 = (size_t)c * 16384;
        gemm256<2><<<dim3(1024), 512, 0, stream>>>(bufA + r0 * EMBED, wm1, b1, bufB, nullptr,
                                                   16384, 4 * EMBED, EMBED);
        gemm256<3><<<dim3(256), 512, 0, stream>>>(bufB, wm2, b2, out + r0 * EMBED, nullptr,
                                                  16384, EMBED, 4 * EMBED);
    }
}

// Round 8
// 1137.118 us; speedup vs baseline: 1.1604x; 1.0126x over previous
//
#include <hip/hip_runtime.h>
#include <cstdint>
#include <cstddef>

// ---- problem constants ----
#define SEQ_L   4096
#define EMBED   1024
#define HEADS   16
#define WINSZ   128
#define SHIFTSZ 64
#define HD      64
#define NWIN    32
#define MTOT    32768          // B * L
#define ATT_SCALE 0.125f       // HD^-0.5

typedef __bf16 bf16x8 __attribute__((ext_vector_type(8)));
typedef float  f32x4  __attribute__((ext_vector_type(4)));

typedef __attribute__((address_space(3))) void       lds_void;
typedef const __attribute__((address_space(1))) void gbl_void;

// async global->LDS, 16B per lane; LDS dest is wave-uniform base + lane*16
#define GLDS16(g, s) __builtin_amdgcn_global_load_lds((gbl_void*)(g), (lds_void*)(s), 16, 0, 0)

__device__ __forceinline__ unsigned short f2bf(float f) {
    unsigned int u = __float_as_uint(f);
    u += 0x7fffu + ((u >> 16) & 1u);   // round-to-nearest-even
    return (unsigned short)(u >> 16);
}

// ---------------- weight f32 -> bf16 (4 tensors in one launch) ----------------
__launch_bounds__(256)
__global__ void wconv4(const float* __restrict__ s0, const float* __restrict__ s1,
                       const float* __restrict__ s2, const float* __restrict__ s3,
                       unsigned short* __restrict__ d0, unsigned short* __restrict__ d1,
                       unsigned short* __restrict__ d2, unsigned short* __restrict__ d3)
{
    const int b = blockIdx.x;
    const float* s; unsigned short* d; int off;
    if (b < 3072)      { s = s0; d = d0; off = b; }
    else if (b < 4096) { s = s1; d = d1; off = b - 3072; }
    else if (b < 8192) { s = s2; d = d2; off = b - 4096; }
    else               { s = s3; d = d3; off = b - 8192; }
    const int i = (off * 256 + threadIdx.x) * 4;
    const float4 v = *(const float4*)(s + i);
    ushort4 o;
    o.x = f2bf(v.x); o.y = f2bf(v.y); o.z = f2bf(v.z); o.w = f2bf(v.w);
    *(ushort4*)(d + i) = o;
}

// ---------------- LayerNorm, wave-per-row (optionally fused with roll) ----------------
__launch_bounds__(256)
__global__ void ln_kernel(const float* __restrict__ x, const float* __restrict__ gw,
                          const float* __restrict__ gb, unsigned short* __restrict__ out,
                          int shift)
{
    const int row  = blockIdx.x * 4 + (threadIdx.x >> 6);
    const int lane = threadIdx.x & 63;
    const int b    = row >> 12;
    const int lw   = row & 4095;
    const int src  = (b << 12) | ((lw + shift) & 4095);
    const float* xr = x + (size_t)src * EMBED;

    float4 v[4];
    float s = 0.f, q = 0.f;
#pragma unroll
    for (int j = 0; j < 4; ++j) {
        v[j] = ((const float4*)xr)[lane + j * 64];
        s += v[j].x + v[j].y + v[j].z + v[j].w;
        q += v[j].x * v[j].x + v[j].y * v[j].y + v[j].z * v[j].z + v[j].w * v[j].w;
    }
#pragma unroll
    for (int off = 32; off > 0; off >>= 1) {
        s += __shfl_xor(s, off);
        q += __shfl_xor(q, off);
    }
    const float mean = s * (1.0f / 1024.0f);
    const float rstd = rsqrtf(q * (1.0f / 1024.0f) - mean * mean + 1e-5f);

    unsigned short* orow = out + (size_t)row * EMBED;
#pragma unroll
    for (int j = 0; j < 4; ++j) {
        const float4 w4 = ((const float4*)gw)[lane + j * 64];
        const float4 b4 = ((const float4*)gb)[lane + j * 64];
        ushort4 o;
        o.x = f2bf((v[j].x - mean) * rstd * w4.x + b4.x);
        o.y = f2bf((v[j].y - mean) * rstd * w4.y + b4.y);
        o.z = f2bf((v[j].z - mean) * rstd * w4.z + b4.z);
        o.w = f2bf((v[j].w - mean) * rstd * w4.w + b4.w);
        ((ushort4*)orow)[lane + j * 64] = o;
    }
}

// ===== 256x256 GEMM: 3-barrier/tile skewed pipeline, formally race-free =====
// out[M,N] = A[M,K](bf16) * W[N,K]^T(bf16) + bias.
// EPI 0: bf16 out (QKV) | EPI 1: f32 out=x[rolled]+v at rolled row (proj)
// EPI 2: gelu->bf16 (MLP1) | EPI 3: f32 out += v (MLP2 residual)
//
// Stage slots: p0: A(t+1) both halves (4 loads); p1: B0(t+2); p2: B1(t+2).
// p2 has the single counted vmcnt(4) (drains B(t+1)+A(t+1), leaves B(t+2))
// BEFORE the p2 barrier -> every wave confirms its staged portions >=1 barrier
// before any consumer ds_read (p3's LOAD_A/LOAD_B). Barriers only at p0/p2/p3
// ends: waves skew across p1..p3, overlapping the LDS and MFMA pipes that the
// old 4-barrier lockstep serialized. WAR ledger: B(t) reads drain at p0's
// lgkm(4) before p0-barrier, restaged p1/p2 (>=1 barrier later); A(t-1) reads
// drain at t-1.p3's lgkm(4) before its barrier, restaged t.p0.

__device__ __forceinline__ void stage_half(const unsigned short* __restrict__ g, int ldk,
                                           char* ldsbase, int tid)
{
    const int r  = tid >> 3;                    // 0..63
    const int cg = ((tid & 7) ^ (r & 7)) << 3;  // inverse-swizzled col (elems)
    GLDS16(g + (size_t)r        * ldk + cg, ldsbase + tid * 16);
    GLDS16(g + (size_t)(r + 64) * ldk + cg, ldsbase + 8192 + tid * 16);
}

__device__ __forceinline__ bf16x8 lds_frag(const char* half, int row, int koff)
{
    const int off = koff ^ ((row & 7) << 4);    // st-swizzle on read
    return *(const bf16x8*)(half + row * 128 + off);
}

template<int EPI>
__launch_bounds__(512, 2)
__global__ void gemm256(const unsigned short* __restrict__ A, const unsigned short* __restrict__ W,
                        const float* __restrict__ bias, void* __restrict__ outv,
                        const float* __restrict__ resid, int M, int N, int K)
{
    __shared__ __align__(16) char lds[131072];
    const int tid = threadIdx.x;
    const int l   = tid & 63, w = tid >> 6;
    const int wm  = w >> 2, wn = w & 3;          // 2 x 4 waves
    const int lr  = l & 15, hi = l >> 4;
    const int k0off = hi << 4;                   // byte offset of k-slice within row
    const int br0   = (wn & 1) << 6;

    // XCD-aware bijective swizzle (all grids here are %8 == 0)
    int id = blockIdx.x;
    const int nwg = gridDim.x;
    id = (id & 7) * (nwg >> 3) + (id >> 3);
    const int Ntl = N >> 8;
    const int m0  = (id / Ntl) << 8;
    const int n0  = (id % Ntl) << 8;
    const int NT  = K >> 6;                      // K-tiles of 64

#define HTB(b, ab, h) (lds + ((((b) << 1 | (ab)) << 1 | (h)) << 14))

    // prologue: t0 {A0,A1,B0,B1}, t1 {B0,B1}; drain t0 (vmcnt(4))
    stage_half(A + (size_t)m0         * K,      K, HTB(0,0,0), tid);
    stage_half(A + (size_t)(m0 + 128) * K,      K, HTB(0,0,1), tid);
    stage_half(W + (size_t)n0         * K,      K, HTB(0,1,0), tid);
    stage_half(W + (size_t)(n0 + 128) * K,      K, HTB(0,1,1), tid);
    stage_half(W + (size_t)n0         * K + 64, K, HTB(1,1,0), tid);
    stage_half(W + (size_t)(n0 + 128) * K + 64, K, HTB(1,1,1), tid);
    asm volatile("s_waitcnt vmcnt(4)" ::: "memory");
    __builtin_amdgcn_s_barrier();

    f32x4 acc[8][4];
#pragma unroll
    for (int f = 0; f < 8; ++f)
#pragma unroll
        for (int n = 0; n < 4; ++n)
            acc[f][n] = (f32x4){0.f, 0.f, 0.f, 0.f};

    bf16x8 bf[4][2], af0[2][2], af1[2][2];

#define LOAD_A_BANK(bank, AHP, F0)                                          \
    af##bank[0][0] = lds_frag(AHP, (F0) * 16 + lr,      k0off);             \
    af##bank[0][1] = lds_frag(AHP, (F0) * 16 + lr,      64 + k0off);        \
    af##bank[1][0] = lds_frag(AHP, (F0) * 16 + 16 + lr, k0off);             \
    af##bank[1][1] = lds_frag(AHP, (F0) * 16 + 16 + lr, 64 + k0off);

#define MFMA_BANK(bank, F0)                                                 \
    __builtin_amdgcn_s_setprio(1);                                          \
    _Pragma("unroll")                                                       \
    for (int n = 0; n < 4; ++n) {                                           \
        acc[F0][n]       = __builtin_amdgcn_mfma_f32_16x16x32_bf16(af##bank[0][0], bf[n][0], acc[F0][n], 0, 0, 0);       \
        acc[F0][n]       = __builtin_amdgcn_mfma_f32_16x16x32_bf16(af##bank[0][1], bf[n][1], acc[F0][n], 0, 0, 0);       \
        acc[(F0) + 1][n] = __builtin_amdgcn_mfma_f32_16x16x32_bf16(af##bank[1][0], bf[n][0], acc[(F0) + 1][n], 0, 0, 0); \
        acc[(F0) + 1][n] = __builtin_amdgcn_mfma_f32_16x16x32_bf16(af##bank[1][1], bf[n][1], acc[(F0) + 1][n], 0, 0, 0); \
    }                                                                       \
    __builtin_amdgcn_s_setprio(0);

    // pre-issue t0.p0 operands: B(0) + A-bank0 f0,f1
    {
        const char* Bh0 = HTB(0, 1, wn >> 1);
#pragma unroll
        for (int n = 0; n < 4; ++n) {
            bf[n][0] = lds_frag(Bh0, br0 + n * 16 + lr, k0off);
            bf[n][1] = lds_frag(Bh0, br0 + n * 16 + lr, 64 + k0off);
        }
        const char* Ah0 = HTB(0, 0, wm);
        LOAD_A_BANK(0, Ah0, 0)
    }

#define TILE(BUF)                                                              \
    {                                                                          \
        const char* Ah = HTB(BUF, 0, wm);                                      \
        const unsigned short* An = A + (size_t)m0 * K + (size_t)(t + 1) * 64;  \
        const unsigned short* Wn = W + (size_t)n0 * K + (size_t)(t + 2) * 64;  \
        /* ---- phase 0: stage A(t+1) fully ---- */                            \
        LOAD_A_BANK(1, Ah, 2)                                                  \
        if (t + 1 < NT) {                                                      \
            stage_half(An,                  K, HTB(BUF ^ 1, 0, 0), tid);       \
            stage_half(An + (size_t)128 * K, K, HTB(BUF ^ 1, 0, 1), tid);      \
        }                                                                      \
        asm volatile("s_waitcnt lgkmcnt(4)" ::: "memory");                     \
        MFMA_BANK(0, 0)                                                        \
        __builtin_amdgcn_s_barrier();                                          \
        /* ---- phase 1: stage B0(t+2), no barrier ---- */                     \
        LOAD_A_BANK(0, Ah, 4)                                                  \
        if (t + 2 < NT) stage_half(Wn, K, HTB(BUF, 1, 0), tid);                \
        asm volatile("s_waitcnt lgkmcnt(4)" ::: "memory");                     \
        MFMA_BANK(1, 2)                                                        \
        /* ---- phase 2: stage B1(t+2); counted vmcnt BEFORE barrier ---- */   \
        LOAD_A_BANK(1, Ah, 6)                                                  \
        if (t + 2 < NT) stage_half(Wn + (size_t)128 * K, K, HTB(BUF, 1, 1), tid); \
        if (t + 2 < NT) { asm volatile("s_waitcnt vmcnt(4)" ::: "memory"); }   \
        else            { asm volatile("s_waitcnt vmcnt(0)" ::: "memory"); }   \
        asm volatile("s_waitcnt lgkmcnt(4)" ::: "memory");                     \
        MFMA_BANK(0, 4)                                                        \
        __builtin_amdgcn_s_barrier();                                          \
        /* ---- phase 3: consume next tile's confirmed data ---- */            \
        if (t + 1 < NT) { const char* AhN = HTB(BUF ^ 1, 0, wm); LOAD_A_BANK(0, AhN, 0) } \
        if (t + 1 < NT) { asm volatile("s_waitcnt lgkmcnt(4)" ::: "memory"); } \
        else            { asm volatile("s_waitcnt lgkmcnt(0)" ::: "memory"); } \
        MFMA_BANK(1, 6)                                                        \
        if (t + 1 < NT) {                                                      \
            const char* BhN = HTB(BUF ^ 1, 1, wn >> 1);                        \
            _Pragma("unroll")                                                  \
            for (int n = 0; n < 4; ++n) {                                      \
                bf[n][0] = lds_frag(BhN, br0 + n * 16 + lr, k0off);            \
                bf[n][1] = lds_frag(BhN, br0 + n * 16 + lr, 64 + k0off);       \
            }                                                                  \
        }                                                                      \
        __builtin_amdgcn_s_barrier();                                          \
    }

    int t;
    for (int u = 0; u < (NT >> 1); ++u) {
        t = 2 * u;     TILE(0)
        t = 2 * u + 1; TILE(1)
    }
#undef TILE
#undef LOAD_A_BANK
#undef MFMA_BANK
#undef HTB

    // ---- epilogue ----
    const int cb = n0 + wn * 64;
    float bv[4];
#pragma unroll
    for (int n = 0; n < 4; ++n) bv[n] = bias[cb + n * 16 + lr];

#pragma unroll
    for (int f = 0; f < 8; ++f) {
        const int mbase = m0 + wm * 128 + f * 16 + hi * 4;
#pragma unroll
        for (int n = 0; n < 4; ++n) {
            const int col = cb + n * 16 + lr;
#pragma unroll
            for (int r = 0; r < 4; ++r) {
                const int m = mbase + r;
                float v = acc[f][n][r] + bv[n];
                if constexpr (EPI == 0) {
                    ((unsigned short*)outv)[(size_t)m * N + col] = f2bf(v);
                } else if constexpr (EPI == 1) {
                    const int bb = m >> 12;
                    const int lw = m & 4095;
                    const int ll = (lw + SHIFTSZ) & 4095;
                    const size_t di = ((size_t)(bb << 12) + ll) * (size_t)N + col;
                    ((float*)outv)[di] = resid[di] + v;
                } else if constexpr (EPI == 2) {
                    const float g = 0.5f * v * (1.0f + erff(v * 0.70710678118654752f));
                    ((unsigned short*)outv)[(size_t)m * N + col] = f2bf(g);
                } else {
                    float* o = (float*)outv;
                    const size_t di = (size_t)m * N + col;
                    o[di] = o[di] + v;
                }
            }
        }
    }
}

// ---------------- windowed attention: one block per (window, head) ----------------
// LDS overlay: P (34 KB) reuses the dead Ks region after QK^T (extra barrier
// between QK^T and softmax makes it safe). Total 52 KB -> 3 blocks/CU.
// Layout: [0,16384) Ks | [0,34816) P (phase 2) | [34816,52224) VT | [52224,+1KB) rpb
#define SM_VT  34816
#define SM_RPB 52224

__device__ __forceinline__ bf16x8 vt_frag(const char* vt, int d, int kbyte)
{
    const int key = ((d >> 3) & 7) << 4;
    return *(const bf16x8*)(vt + d * 272 + (kbyte ^ key));
}

__launch_bounds__(256, 3)
__global__ void attn_kernel(const unsigned short* __restrict__ qkv, const float* __restrict__ rpb,
                            unsigned short* __restrict__ outp)
{
    __shared__ __align__(16) char smem[53248];

    const int t   = threadIdx.x;
    const int l   = t & 63;
    const int w   = t >> 6;
    const int lr  = l & 15;
    const int lq  = l >> 4;
    const int lk  = lq * 8;
    const int blk = blockIdx.x;
    const int win = blk >> 4;
    const int h   = blk & 15;
    const bool masked = ((win & (NWIN - 1)) == NWIN - 1);

    const unsigned short* qb = qkv + (size_t)(win * WINSZ) * (3 * EMBED) + h * HD;
    const unsigned short* kb = qb + EMBED;
    const unsigned short* vb = qb + 2 * EMBED;
    const int mrow = w * 32;
    float* rpbl = (float*)(smem + SM_RPB);

    // ---- hoist Q fragment loads (latency hides under K/V staging) ----
    bf16x8 aqr[2][2];
#pragma unroll
    for (int ks = 0; ks < 2; ++ks)
#pragma unroll
        for (int mi = 0; mi < 2; ++mi)
            aqr[ks][mi] = *(const bf16x8*)(qb + (size_t)(mrow + mi * 16 + lr) * (3 * EMBED) + ks * 32 + lk);

    // ---- stage rpb column h ----
    if (t < 255) rpbl[t] = rpb[t * HEADS + h];

    // ---- stage K: inverse-swizzled source, linear LDS dest (bytes 0..16K) ----
    {
        const int c = t & 7;
#pragma unroll
        for (int p = 0; p < 4; ++p) {
            const int r  = (t >> 3) + p * 32;
            const int cg = (c ^ (r & 7)) << 3;
            GLDS16(kb + (size_t)r * (3 * EMBED) + cg, smem + p * 4096 + t * 16);
        }
    }
    // ---- stage V^T: coalesced reads, swizzled transpose writes ----
    {
        const int c = t & 7;
#pragma unroll
        for (int p = 0; p < 4; ++p) {
            const int k = (t >> 3) + p * 32;
            const uint4 v = *(const uint4*)(vb + (size_t)k * (3 * EMBED) + c * 8);
            const unsigned int vals[4] = {v.x, v.y, v.z, v.w};
            char* base = smem + SM_VT;
#pragma unroll
            for (int e2 = 0; e2 < 4; ++e2) {
                const int d0 = c * 8 + e2 * 2;
                const int key = c << 4;
                *(unsigned short*)(base + d0 * 272 + ((2 * k) ^ key))       = (unsigned short)(vals[e2] & 0xffff);
                *(unsigned short*)(base + (d0 + 1) * 272 + ((2 * k) ^ key)) = (unsigned short)(vals[e2] >> 16);
            }
        }
    }
    asm volatile("s_waitcnt vmcnt(0)" ::: "memory");
    __syncthreads();

    // ---- QK^T ----
    f32x4 sacc[2][8];
#pragma unroll
    for (int a = 0; a < 2; ++a)
#pragma unroll
        for (int b = 0; b < 8; ++b)
            sacc[a][b] = (f32x4){0.f, 0.f, 0.f, 0.f};

#pragma unroll
    for (int ks = 0; ks < 2; ++ks) {
        const int kby = ks * 64 + lq * 16;
        bf16x8 bk8[8];
#pragma unroll
        for (int ni = 0; ni < 8; ++ni)
            bk8[ni] = lds_frag(smem, ni * 16 + lr, kby);
#pragma unroll
        for (int mi = 0; mi < 2; ++mi)
#pragma unroll
            for (int ni = 0; ni < 8; ++ni)
                sacc[mi][ni] = __builtin_amdgcn_mfma_f32_16x16x32_bf16(aqr[ks][mi], bk8[ni], sacc[mi][ni], 0, 0, 0);
    }

    __syncthreads();   // K region dead everywhere -> P may overlay it

    // ---- in-register softmax per row; P -> smem[0..34816) ----
#pragma unroll
    for (int mi = 0; mi < 2; ++mi)
#pragma unroll
        for (int r = 0; r < 4; ++r) {
            const int i = mrow + mi * 16 + lq * 4 + r;
            float v[8];
            float mx = -1e30f;
#pragma unroll
            for (int ni = 0; ni < 8; ++ni) {
                const int j = ni * 16 + lr;
                float sv = sacc[mi][ni][r] * ATT_SCALE + rpbl[j - i + WINSZ - 1];
                if (masked && ((i >= SHIFTSZ) != (j >= SHIFTSZ))) sv -= 100.0f;
                v[ni] = sv;
                mx = fmaxf(mx, sv);
            }
#pragma unroll
            for (int s = 1; s < 16; s <<= 1) mx = fmaxf(mx, __shfl_xor(mx, s));
            float sm = 0.f;
#pragma unroll
            for (int ni = 0; ni < 8; ++ni) {
                const float p = __expf(v[ni] - mx);
                v[ni] = p;
                sm += p;
            }
#pragma unroll
            for (int s = 1; s < 16; s <<= 1) sm += __shfl_xor(sm, s);
            const float rs = 1.0f / sm;
#pragma unroll
            for (int ni = 0; ni < 8; ++ni)
                *(unsigned short*)(smem + ((size_t)i * 136 + ni * 16 + lr) * 2) = f2bf(v[ni] * rs);
        }

    __syncthreads();

    // ---- PV ----
    f32x4 oacc[2][4];
#pragma unroll
    for (int a = 0; a < 2; ++a)
#pragma unroll
        for (int b = 0; b < 4; ++b)
            oacc[a][b] = (f32x4){0.f, 0.f, 0.f, 0.f};

#pragma unroll
    for (int ks = 0; ks < 4; ++ks) {
        const int k0 = ks * 32;
        bf16x8 ap[2], av[4];
#pragma unroll
        for (int mi = 0; mi < 2; ++mi)
            ap[mi] = *(const bf16x8*)(smem + ((size_t)(mrow + mi * 16 + lr) * 136 + k0 + lk) * 2);
#pragma unroll
        for (int ni = 0; ni < 4; ++ni)
            av[ni] = vt_frag(smem + SM_VT, ni * 16 + lr, k0 * 2 + lq * 16);
#pragma unroll
        for (int mi = 0; mi < 2; ++mi)
#pragma unroll
            for (int ni = 0; ni < 4; ++ni)
                oacc[mi][ni] = __builtin_amdgcn_mfma_f32_16x16x32_bf16(ap[mi], av[ni], oacc[mi][ni], 0, 0, 0);
    }

    unsigned short* ob = outp + (size_t)(win * WINSZ) * EMBED + h * HD;
#pragma unroll
    for (int mi = 0; mi < 2; ++mi)
#pragma unroll
        for (int ni = 0; ni < 4; ++ni)
#pragma unroll
            for (int r = 0; r < 4; ++r) {
                const int i = mrow + mi * 16 + lq * 4 + r;
                const int d = ni * 16 + lr;
                ob[(size_t)i * EMBED + d] = f2bf(oacc[mi][ni][r]);
            }
}

// ---------------- launcher ----------------
extern "C" void kernel_launch(void* const* d_in, const int* in_sizes, int n_in,
                              void* d_out, int out_size, void* d_ws, size_t ws_size,
                              hipStream_t stream)
{
    const float* x      = (const float*)d_in[0];
    const float* qkv_w  = (const float*)d_in[1];
    const float* qkv_b  = (const float*)d_in[2];
    const float* proj_w = (const float*)d_in[3];
    const float* proj_b = (const float*)d_in[4];
    const float* rpb    = (const float*)d_in[5];
    const float* n1w    = (const float*)d_in[6];
    const float* n1b    = (const float*)d_in[7];
    const float* n2w    = (const float*)d_in[8];
    const float* n2b    = (const float*)d_in[9];
    const float* w1     = (const float*)d_in[10];
    const float* b1     = (const float*)d_in[11];
    const float* w2     = (const float*)d_in[12];
    const float* b2     = (const float*)d_in[13];
    float* out = (float*)d_out;

    unsigned short* wqkv  = (unsigned short*)d_ws;                    // 3072*1024
    unsigned short* wproj = wqkv  + (size_t)3072 * 1024;              // 1024*1024
    unsigned short* wm1   = wproj + (size_t)1024 * 1024;              // 4096*1024
    unsigned short* wm2   = wm1   + (size_t)4096 * 1024;              // 4096*1024
    unsigned short* bufA  = wm2   + (size_t)4096 * 1024;              // 32768*1024
    unsigned short* bufB  = bufA  + (size_t)MTOT * EMBED;             // 32768*3072

    // all 4 weight conversions in one launch
    wconv4<<<12288, 256, 0, stream>>>(qkv_w, proj_w, w1, w2, wqkv, wproj, wm1, wm2);

    // h = LN1(x) rolled by -SHIFT
    ln_kernel<<<8192, 256, 0, stream>>>(x, n1w, n1b, bufA, SHIFTSZ);

    // qkv = h @ qkv_w^T + qkv_b   (M=32768, N=3072, K=1024)
    gemm256<0><<<dim3(1536), 512, 0, stream>>>(bufA, wqkv, qkv_b, bufB, nullptr, MTOT, 3 * EMBED, EMBED);

    // windowed attention -> bufA
    attn_kernel<<<4096, 256, 0, stream>>>(bufB, rpb, bufA);

    // x2 = x + roll(attn @ proj_w^T + proj_b, +SHIFT)
    gemm256<1><<<dim3(512), 512, 0, stream>>>(bufA, wproj, proj_b, out, x, MTOT, EMBED, EMBED);

    // h2 = LN2(x2)
    ln_kernel<<<8192, 256, 0, stream>>>(out, n2w, n2b, bufA, 0);

    // MLP chunked (2 x 16384 rows)
    for (int c = 0; c < 2; ++c) {
        const size_t r0 = (size_t)c * 16384;
        gemm256<2><<<dim3(1024), 512, 0, stream>>>(bufA + r0 * EMBED, wm1, b1, bufB, nullptr,
                                                   16384, 4 * EMBED, EMBED);
        gemm256<3><<<dim3(256), 512, 0, stream>>>(bufB, wm2, b2, out + r0 * EMBED, nullptr,
                                                  16384, EMBED, 4 * EMBED);
    }
}

// Round 9
// 1137.104 us; speedup vs baseline: 1.1604x; 1.0000x over previous
//
#include <hip/hip_runtime.h>
#include <cstdint>
#include <cstddef>

// ---- problem constants ----
#define SEQ_L   4096
#define EMBED   1024
#define HEADS   16
#define WINSZ   128
#define SHIFTSZ 64
#define HD      64
#define NWIN    32
#define MTOT    32768          // B * L
#define ATT_SCALE 0.125f       // HD^-0.5

typedef __bf16 bf16x8 __attribute__((ext_vector_type(8)));
typedef float  f32x4  __attribute__((ext_vector_type(4)));

typedef __attribute__((address_space(3))) void       lds_void;
typedef const __attribute__((address_space(1))) void gbl_void;

// async global->LDS, 16B per lane; LDS dest is wave-uniform base + lane*16
#define GLDS16(g, s) __builtin_amdgcn_global_load_lds((gbl_void*)(g), (lds_void*)(s), 16, 0, 0)

__device__ __forceinline__ unsigned short f2bf(float f) {
    unsigned int u = __float_as_uint(f);
    u += 0x7fffu + ((u >> 16) & 1u);   // round-to-nearest-even
    return (unsigned short)(u >> 16);
}

// ---------------- weight f32 -> bf16 (4 tensors in one launch) ----------------
__launch_bounds__(256)
__global__ void wconv4(const float* __restrict__ s0, const float* __restrict__ s1,
                       const float* __restrict__ s2, const float* __restrict__ s3,
                       unsigned short* __restrict__ d0, unsigned short* __restrict__ d1,
                       unsigned short* __restrict__ d2, unsigned short* __restrict__ d3)
{
    const int b = blockIdx.x;
    const float* s; unsigned short* d; int off;
    if (b < 3072)      { s = s0; d = d0; off = b; }
    else if (b < 4096) { s = s1; d = d1; off = b - 3072; }
    else if (b < 8192) { s = s2; d = d2; off = b - 4096; }
    else               { s = s3; d = d3; off = b - 8192; }
    const int i = (off * 256 + threadIdx.x) * 4;
    const float4 v = *(const float4*)(s + i);
    ushort4 o;
    o.x = f2bf(v.x); o.y = f2bf(v.y); o.z = f2bf(v.z); o.w = f2bf(v.w);
    *(ushort4*)(d + i) = o;
}

// ---------------- LayerNorm, wave-per-row (optionally fused with roll) ----------------
__launch_bounds__(256)
__global__ void ln_kernel(const float* __restrict__ x, const float* __restrict__ gw,
                          const float* __restrict__ gb, unsigned short* __restrict__ out,
                          int shift)
{
    const int row  = blockIdx.x * 4 + (threadIdx.x >> 6);
    const int lane = threadIdx.x & 63;
    const int b    = row >> 12;
    const int lw   = row & 4095;
    const int src  = (b << 12) | ((lw + shift) & 4095);
    const float* xr = x + (size_t)src * EMBED;

    float4 v[4];
    float s = 0.f, q = 0.f;
#pragma unroll
    for (int j = 0; j < 4; ++j) {
        v[j] = ((const float4*)xr)[lane + j * 64];
        s += v[j].x + v[j].y + v[j].z + v[j].w;
        q += v[j].x * v[j].x + v[j].y * v[j].y + v[j].z * v[j].z + v[j].w * v[j].w;
    }
#pragma unroll
    for (int off = 32; off > 0; off >>= 1) {
        s += __shfl_xor(s, off);
        q += __shfl_xor(q, off);
    }
    const float mean = s * (1.0f / 1024.0f);
    const float rstd = rsqrtf(q * (1.0f / 1024.0f) - mean * mean + 1e-5f);

    unsigned short* orow = out + (size_t)row * EMBED;
#pragma unroll
    for (int j = 0; j < 4; ++j) {
        const float4 w4 = ((const float4*)gw)[lane + j * 64];
        const float4 b4 = ((const float4*)gb)[lane + j * 64];
        ushort4 o;
        o.x = f2bf((v[j].x - mean) * rstd * w4.x + b4.x);
        o.y = f2bf((v[j].y - mean) * rstd * w4.y + b4.y);
        o.z = f2bf((v[j].z - mean) * rstd * w4.z + b4.z);
        o.w = f2bf((v[j].w - mean) * rstd * w4.w + b4.w);
        ((ushort4*)orow)[lane + j * 64] = o;
    }
}

// ===== 256x256 GEMM: max-skew pipeline, ONE barrier per K-tile =====
// out[M,N] = A[M,K](bf16) * W[N,K]^T(bf16) + bias.
// EPI 0: bf16 out (QKV) | EPI 1: f32 out=x[rolled]+v at rolled row (proj)
// EPI 2: gelu->bf16 (MLP1) | EPI 3: f32 out += v (MLP2 residual)
//
// Tile t reads buf b=t&1; the FULL tile t+1 (A+B, 8 gloads/thread) is staged
// into buf b^1 at tile start. Within a tile there are NO barriers: waves skew
// freely (64 MFMA + 24 ds_reads of independent work), so co-resident waves on
// a SIMD fill each other's lgkm stalls. End of tile: vmcnt(0) (stage loads
// issued a whole tile earlier -> latency hidden) + one barrier.
// WAR: after the tile barrier, no wave reads b^1 (each wave's reads returned
// before its own lgkmcnt(0)+barrier), so staging b^1 is safe; RAW: buf b was
// vmcnt(0)-drained + barriered at the end of tile t-1.

__device__ __forceinline__ void stage_half(const unsigned short* __restrict__ g, int ldk,
                                           char* ldsbase, int tid)
{
    const int r  = tid >> 3;                    // 0..63
    const int cg = ((tid & 7) ^ (r & 7)) << 3;  // inverse-swizzled col (elems)
    GLDS16(g + (size_t)r        * ldk + cg, ldsbase + tid * 16);
    GLDS16(g + (size_t)(r + 64) * ldk + cg, ldsbase + 8192 + tid * 16);
}

__device__ __forceinline__ bf16x8 lds_frag(const char* half, int row, int koff)
{
    const int off = koff ^ ((row & 7) << 4);    // st-swizzle on read
    return *(const bf16x8*)(half + row * 128 + off);
}

template<int EPI>
__launch_bounds__(512, 2)
__global__ void gemm256(const unsigned short* __restrict__ A, const unsigned short* __restrict__ W,
                        const float* __restrict__ bias, void* __restrict__ outv,
                        const float* __restrict__ resid, int M, int N, int K)
{
    __shared__ __align__(16) char lds[131072];
    const int tid = threadIdx.x;
    const int l   = tid & 63, w = tid >> 6;
    const int wm  = w >> 2, wn = w & 3;          // 2 x 4 waves
    const int lr  = l & 15, hi = l >> 4;
    const int k0off = hi << 4;                   // byte offset of k-slice within row
    const int br0   = (wn & 1) << 6;

    // XCD-aware bijective swizzle (all grids here are %8 == 0)
    int id = blockIdx.x;
    const int nwg = gridDim.x;
    id = (id & 7) * (nwg >> 3) + (id >> 3);
    const int Ntl = N >> 8;
    const int m0  = (id / Ntl) << 8;
    const int n0  = (id % Ntl) << 8;
    const int NT  = K >> 6;                      // K-tiles of 64 (even)

#define HTB(b, ab, h) (lds + ((((b) << 1 | (ab)) << 1 | (h)) << 14))

    // prologue: stage tile 0 fully; drain; barrier
    stage_half(A + (size_t)m0         * K, K, HTB(0,0,0), tid);
    stage_half(A + (size_t)(m0 + 128) * K, K, HTB(0,0,1), tid);
    stage_half(W + (size_t)n0         * K, K, HTB(0,1,0), tid);
    stage_half(W + (size_t)(n0 + 128) * K, K, HTB(0,1,1), tid);
    asm volatile("s_waitcnt vmcnt(0)" ::: "memory");
    __builtin_amdgcn_s_barrier();

    f32x4 acc[8][4];
#pragma unroll
    for (int f = 0; f < 8; ++f)
#pragma unroll
        for (int n = 0; n < 4; ++n)
            acc[f][n] = (f32x4){0.f, 0.f, 0.f, 0.f};

    bf16x8 bf[4][2], af0[2][2], af1[2][2];

#define LOAD_A_BANK(bank, AHP, F0)                                          \
    af##bank[0][0] = lds_frag(AHP, (F0) * 16 + lr,      k0off);             \
    af##bank[0][1] = lds_frag(AHP, (F0) * 16 + lr,      64 + k0off);        \
    af##bank[1][0] = lds_frag(AHP, (F0) * 16 + 16 + lr, k0off);             \
    af##bank[1][1] = lds_frag(AHP, (F0) * 16 + 16 + lr, 64 + k0off);

#define MFMA_BANK(bank, F0)                                                 \
    __builtin_amdgcn_s_setprio(1);                                          \
    _Pragma("unroll")                                                       \
    for (int n = 0; n < 4; ++n) {                                           \
        acc[F0][n]       = __builtin_amdgcn_mfma_f32_16x16x32_bf16(af##bank[0][0], bf[n][0], acc[F0][n], 0, 0, 0);       \
        acc[F0][n]       = __builtin_amdgcn_mfma_f32_16x16x32_bf16(af##bank[0][1], bf[n][1], acc[F0][n], 0, 0, 0);       \
        acc[(F0) + 1][n] = __builtin_amdgcn_mfma_f32_16x16x32_bf16(af##bank[1][0], bf[n][0], acc[(F0) + 1][n], 0, 0, 0); \
        acc[(F0) + 1][n] = __builtin_amdgcn_mfma_f32_16x16x32_bf16(af##bank[1][1], bf[n][1], acc[(F0) + 1][n], 0, 0, 0); \
    }                                                                       \
    __builtin_amdgcn_s_setprio(0);

#define TILE(BUF)                                                              \
    {                                                                          \
        const char* Ah = HTB(BUF, 0, wm);                                      \
        const char* Bh = HTB(BUF, 1, wn >> 1);                                 \
        /* B-frags + A f0,f1 */                                                \
        _Pragma("unroll")                                                      \
        for (int n = 0; n < 4; ++n) {                                          \
            bf[n][0] = lds_frag(Bh, br0 + n * 16 + lr, k0off);                 \
            bf[n][1] = lds_frag(Bh, br0 + n * 16 + lr, 64 + k0off);            \
        }                                                                      \
        LOAD_A_BANK(0, Ah, 0)                                                  \
        /* stage full tile t+1 into buf^1 */                                   \
        if (t + 1 < NT) {                                                      \
            const unsigned short* An = A + (size_t)m0 * K + (size_t)(t + 1) * 64; \
            const unsigned short* Wn = W + (size_t)n0 * K + (size_t)(t + 1) * 64; \
            stage_half(An,                   K, HTB(BUF ^ 1, 0, 0), tid);      \
            stage_half(An + (size_t)128 * K, K, HTB(BUF ^ 1, 0, 1), tid);      \
            stage_half(Wn,                   K, HTB(BUF ^ 1, 1, 0), tid);      \
            stage_half(Wn + (size_t)128 * K, K, HTB(BUF ^ 1, 1, 1), tid);      \
        }                                                                      \
        LOAD_A_BANK(1, Ah, 2)                                                  \
        asm volatile("s_waitcnt lgkmcnt(4)" ::: "memory");                     \
        MFMA_BANK(0, 0)                                                        \
        LOAD_A_BANK(0, Ah, 4)                                                  \
        asm volatile("s_waitcnt lgkmcnt(4)" ::: "memory");                     \
        MFMA_BANK(1, 2)                                                        \
        LOAD_A_BANK(1, Ah, 6)                                                  \
        asm volatile("s_waitcnt lgkmcnt(4)" ::: "memory");                     \
        MFMA_BANK(0, 4)                                                        \
        asm volatile("s_waitcnt lgkmcnt(0)" ::: "memory");                     \
        MFMA_BANK(1, 6)                                                        \
        asm volatile("s_waitcnt vmcnt(0)" ::: "memory");                       \
        __builtin_amdgcn_s_barrier();                                          \
    }

    int t;
    for (int u = 0; u < (NT >> 1); ++u) {
        t = 2 * u;     TILE(0)
        t = 2 * u + 1; TILE(1)
    }
#undef TILE
#undef LOAD_A_BANK
#undef MFMA_BANK
#undef HTB

    // ---- epilogue ----
    const int cb = n0 + wn * 64;
    float bv[4];
#pragma unroll
    for (int n = 0; n < 4; ++n) bv[n] = bias[cb + n * 16 + lr];

#pragma unroll
    for (int f = 0; f < 8; ++f) {
        const int mbase = m0 + wm * 128 + f * 16 + hi * 4;
#pragma unroll
        for (int n = 0; n < 4; ++n) {
            const int col = cb + n * 16 + lr;
#pragma unroll
            for (int r = 0; r < 4; ++r) {
                const int m = mbase + r;
                float v = acc[f][n][r] + bv[n];
                if constexpr (EPI == 0) {
                    ((unsigned short*)outv)[(size_t)m * N + col] = f2bf(v);
                } else if constexpr (EPI == 1) {
                    const int bb = m >> 12;
                    const int lw = m & 4095;
                    const int ll = (lw + SHIFTSZ) & 4095;
                    const size_t di = ((size_t)(bb << 12) + ll) * (size_t)N + col;
                    ((float*)outv)[di] = resid[di] + v;
                } else if constexpr (EPI == 2) {
                    const float g = 0.5f * v * (1.0f + erff(v * 0.70710678118654752f));
                    ((unsigned short*)outv)[(size_t)m * N + col] = f2bf(g);
                } else {
                    float* o = (float*)outv;
                    const size_t di = (size_t)m * N + col;
                    o[di] = o[di] + v;
                }
            }
        }
    }
}

// ---------------- windowed attention: one block per (window, head) ----------------
// LDS overlay: P (34 KB) reuses the dead Ks region after QK^T. 52 KB -> 3 blocks/CU.
#define SM_VT  34816
#define SM_RPB 52224

__device__ __forceinline__ bf16x8 vt_frag(const char* vt, int d, int kbyte)
{
    const int key = ((d >> 3) & 7) << 4;
    return *(const bf16x8*)(vt + d * 272 + (kbyte ^ key));
}

__launch_bounds__(256, 3)
__global__ void attn_kernel(const unsigned short* __restrict__ qkv, const float* __restrict__ rpb,
                            unsigned short* __restrict__ outp)
{
    __shared__ __align__(16) char smem[53248];

    const int t   = threadIdx.x;
    const int l   = t & 63;
    const int w   = t >> 6;
    const int lr  = l & 15;
    const int lq  = l >> 4;
    const int lk  = lq * 8;
    const int blk = blockIdx.x;
    const int win = blk >> 4;
    const int h   = blk & 15;
    const bool masked = ((win & (NWIN - 1)) == NWIN - 1);

    const unsigned short* qb = qkv + (size_t)(win * WINSZ) * (3 * EMBED) + h * HD;
    const unsigned short* kb = qb + EMBED;
    const unsigned short* vb = qb + 2 * EMBED;
    const int mrow = w * 32;
    float* rpbl = (float*)(smem + SM_RPB);

    // ---- hoist Q fragment loads (latency hides under K/V staging) ----
    bf16x8 aqr[2][2];
#pragma unroll
    for (int ks = 0; ks < 2; ++ks)
#pragma unroll
        for (int mi = 0; mi < 2; ++mi)
            aqr[ks][mi] = *(const bf16x8*)(qb + (size_t)(mrow + mi * 16 + lr) * (3 * EMBED) + ks * 32 + lk);

    // ---- stage rpb column h ----
    if (t < 255) rpbl[t] = rpb[t * HEADS + h];

    // ---- stage K: inverse-swizzled source, linear LDS dest (bytes 0..16K) ----
    {
        const int c = t & 7;
#pragma unroll
        for (int p = 0; p < 4; ++p) {
            const int r  = (t >> 3) + p * 32;
            const int cg = (c ^ (r & 7)) << 3;
            GLDS16(kb + (size_t)r * (3 * EMBED) + cg, smem + p * 4096 + t * 16);
        }
    }
    // ---- stage V^T: coalesced reads, swizzled transpose writes ----
    {
        const int c = t & 7;
#pragma unroll
        for (int p = 0; p < 4; ++p) {
            const int k = (t >> 3) + p * 32;
            const uint4 v = *(const uint4*)(vb + (size_t)k * (3 * EMBED) + c * 8);
            const unsigned int vals[4] = {v.x, v.y, v.z, v.w};
            char* base = smem + SM_VT;
#pragma unroll
            for (int e2 = 0; e2 < 4; ++e2) {
                const int d0 = c * 8 + e2 * 2;
                const int key = c << 4;
                *(unsigned short*)(base + d0 * 272 + ((2 * k) ^ key))       = (unsigned short)(vals[e2] & 0xffff);
                *(unsigned short*)(base + (d0 + 1) * 272 + ((2 * k) ^ key)) = (unsigned short)(vals[e2] >> 16);
            }
        }
    }
    asm volatile("s_waitcnt vmcnt(0)" ::: "memory");
    __syncthreads();

    // ---- QK^T ----
    f32x4 sacc[2][8];
#pragma unroll
    for (int a = 0; a < 2; ++a)
#pragma unroll
        for (int b = 0; b < 8; ++b)
            sacc[a][b] = (f32x4){0.f, 0.f, 0.f, 0.f};

#pragma unroll
    for (int ks = 0; ks < 2; ++ks) {
        const int kby = ks * 64 + lq * 16;
        bf16x8 bk8[8];
#pragma unroll
        for (int ni = 0; ni < 8; ++ni)
            bk8[ni] = lds_frag(smem, ni * 16 + lr, kby);
#pragma unroll
        for (int mi = 0; mi < 2; ++mi)
#pragma unroll
            for (int ni = 0; ni < 8; ++ni)
                sacc[mi][ni] = __builtin_amdgcn_mfma_f32_16x16x32_bf16(aqr[ks][mi], bk8[ni], sacc[mi][ni], 0, 0, 0);
    }

    __syncthreads();   // K region dead everywhere -> P may overlay it

    // ---- in-register softmax per row; P -> smem[0..34816) ----
#pragma unroll
    for (int mi = 0; mi < 2; ++mi)
#pragma unroll
        for (int r = 0; r < 4; ++r) {
            const int i = mrow + mi * 16 + lq * 4 + r;
            float v[8];
            float mx = -1e30f;
#pragma unroll
            for (int ni = 0; ni < 8; ++ni) {
                const int j = ni * 16 + lr;
                float sv = sacc[mi][ni][r] * ATT_SCALE + rpbl[j - i + WINSZ - 1];
                if (masked && ((i >= SHIFTSZ) != (j >= SHIFTSZ))) sv -= 100.0f;
                v[ni] = sv;
                mx = fmaxf(mx, sv);
            }
#pragma unroll
            for (int s = 1; s < 16; s <<= 1) mx = fmaxf(mx, __shfl_xor(mx, s));
            float sm = 0.f;
#pragma unroll
            for (int ni = 0; ni < 8; ++ni) {
                const float p = __expf(v[ni] - mx);
                v[ni] = p;
                sm += p;
            }
#pragma unroll
            for (int s = 1; s < 16; s <<= 1) sm += __shfl_xor(sm, s);
            const float rs = 1.0f / sm;
#pragma unroll
            for (int ni = 0; ni < 8; ++ni)
                *(unsigned short*)(smem + ((size_t)i * 136 + ni * 16 + lr) * 2) = f2bf(v[ni] * rs);
        }

    __syncthreads();

    // ---- PV ----
    f32x4 oacc[2][4];
#pragma unroll
    for (int a = 0; a < 2; ++a)
#pragma unroll
        for (int b = 0; b < 4; ++b)
            oacc[a][b] = (f32x4){0.f, 0.f, 0.f, 0.f};

#pragma unroll
    for (int ks = 0; ks < 4; ++ks) {
        const int k0 = ks * 32;
        bf16x8 ap[2], av[4];
#pragma unroll
        for (int mi = 0; mi < 2; ++mi)
            ap[mi] = *(const bf16x8*)(smem + ((size_t)(mrow + mi * 16 + lr) * 136 + k0 + lk) * 2);
#pragma unroll
        for (int ni = 0; ni < 4; ++ni)
            av[ni] = vt_frag(smem + SM_VT, ni * 16 + lr, k0 * 2 + lq * 16);
#pragma unroll
        for (int mi = 0; mi < 2; ++mi)
#pragma unroll
            for (int ni = 0; ni < 4; ++ni)
                oacc[mi][ni] = __builtin_amdgcn_mfma_f32_16x16x32_bf16(ap[mi], av[ni], oacc[mi][ni], 0, 0, 0);
    }

    unsigned short* ob = outp + (size_t)(win * WINSZ) * EMBED + h * HD;
#pragma unroll
    for (int mi = 0; mi < 2; ++mi)
#pragma unroll
        for (int ni = 0; ni < 4; ++ni)
#pragma unroll
            for (int r = 0; r < 4; ++r) {
                const int i = mrow + mi * 16 + lq * 4 + r;
                const int d = ni * 16 + lr;
                ob[(size_t)i * EMBED + d] = f2bf(oacc[mi][ni][r]);
            }
}

// ---------------- launcher ----------------
extern "C" void kernel_launch(void* const* d_in, const int* in_sizes, int n_in,
                              void* d_out, int out_size, void* d_ws, size_t ws_size,
                              hipStream_t stream)
{
    const float* x      = (const float*)d_in[0];
    const float* qkv_w  = (const float*)d_in[1];
    const float* qkv_b  = (const float*)d_in[2];
    const float* proj_w = (const float*)d_in[3];
    const float* proj_b = (const float*)d_in[4];
    const float* rpb    = (const float*)d_in[5];
    const float* n1w    = (const float*)d_in[6];
    const float* n1b    = (const float*)d_in[7];
    const float* n2w    = (const float*)d_in[8];
    const float* n2b    = (const float*)d_in[9];
    const float* w1     = (const float*)d_in[10];
    const float* b1     = (const float*)d_in[11];
    const float* w2     = (const float*)d_in[12];
    const float* b2     = (const float*)d_in[13];
    float* out = (float*)d_out;

    unsigned short* wqkv  = (unsigned short*)d_ws;                    // 3072*1024
    unsigned short* wproj = wqkv  + (size_t)3072 * 1024;              // 1024*1024
    unsigned short* wm1   = wproj + (size_t)1024 * 1024;              // 4096*1024
    unsigned short* wm2   = wm1   + (size_t)4096 * 1024;              // 4096*1024
    unsigned short* bufA  = wm2   + (size_t)4096 * 1024;              // 32768*1024
    unsigned short* bufB  = bufA  + (size_t)MTOT * EMBED;             // 32768*3072

    // all 4 weight conversions in one launch
    wconv4<<<12288, 256, 0, stream>>>(qkv_w, proj_w, w1, w2, wqkv, wproj, wm1, wm2);

    // h = LN1(x) rolled by -SHIFT
    ln_kernel<<<8192, 256, 0, stream>>>(x, n1w, n1b, bufA, SHIFTSZ);

    // qkv = h @ qkv_w^T + qkv_b   (M=32768, N=3072, K=1024)
    gemm256<0><<<dim3(1536), 512, 0, stream>>>(bufA, wqkv, qkv_b, bufB, nullptr, MTOT, 3 * EMBED, EMBED);

    // windowed attention -> bufA
    attn_kernel<<<4096, 256, 0, stream>>>(bufB, rpb, bufA);

    // x2 = x + roll(attn @ proj_w^T + proj_b, +SHIFT)
    gemm256<1><<<dim3(512), 512, 0, stream>>>(bufA, wproj, proj_b, out, x, MTOT, EMBED, EMBED);

    // h2 = LN2(x2)
    ln_kernel<<<8192, 256, 0, stream>>>(out, n2w, n2b, bufA, 0);

    // MLP chunked (2 x 16384 rows)
    for (int c = 0; c < 2; ++c) {
        const size_t r0 = (size_t)c * 16384;
        gemm256<2><<<dim3(1024), 512, 0, stream>>>(bufA + r0 * EMBED, wm1, b1, bufB, nullptr,
                                                   16384, 4 * EMBED, EMBED);
        gemm256<3><<<dim3(256), 512, 0, stream>>>(bufB, wm2, b2, out + r0 * EMBED, nullptr,
                                                  16384, EMBED, 4 * EMBED);
    }
}